// Round 2
// baseline (483.157 us; speedup 1.0000x reference)
//
#include <hip/hip_runtime.h>
#include <math.h>

#define B_SZ 4
#define N_SEQ 2048
#define D_DIM 256
#define H_HEADS 4
#define E_DIM 256
#define ROWS (B_SZ*N_SEQ)
#define PAD_TOK -2.0f
#define LN_EPS 1e-6f

typedef __attribute__((ext_vector_type(8))) short short8;   // 8 x bf16 (4 VGPRs)
typedef __attribute__((ext_vector_type(4))) float f32x4;

static __device__ __forceinline__ unsigned short f2bf(float f){
  union { float f; unsigned u; } v; v.f = f;
  unsigned r = v.u + 0x7fffu + ((v.u >> 16) & 1u);
  return (unsigned short)(r >> 16);
}
static __device__ __forceinline__ float bf2f(unsigned short s){
  union { unsigned u; float f; } v; v.u = ((unsigned)s) << 16; return v.f;
}
static __device__ __forceinline__ f32x4 mfma16(short8 a, short8 b, f32x4 c){
  return __builtin_amdgcn_mfma_f32_16x16x32_bf16(a, b, c, 0, 0, 0);
}

// ---------------- Kernel 1: input LN -> bf16 x_norm, mask value ----------------
__global__ __launch_bounds__(256) void k_ln_in(
    const float* __restrict__ x, const float* __restrict__ mask,
    const float* __restrict__ g, const float* __restrict__ bta,
    unsigned short* __restrict__ xn, float* __restrict__ mval){
  int row = blockIdx.x * 4 + (threadIdx.x >> 6);
  int lane = threadIdx.x & 63;
  const float* xr = x + (size_t)row * D_DIM + lane * 4;
  f32x4 v = *reinterpret_cast<const f32x4*>(xr);
  float s = v[0]+v[1]+v[2]+v[3];
  float q = v[0]*v[0]+v[1]*v[1]+v[2]*v[2]+v[3]*v[3];
  #pragma unroll
  for (int m=1;m<64;m<<=1){ s += __shfl_xor(s,m,64); q += __shfl_xor(q,m,64); }
  float mean = s * (1.0f/D_DIM);
  float var  = q * (1.0f/D_DIM) - mean*mean;
  float rs = rsqrtf(var + LN_EPS);
  int c = lane*4;
  ushort4 o;
  o.x = f2bf((v[0]-mean)*rs*g[c+0] + bta[c+0]);
  o.y = f2bf((v[1]-mean)*rs*g[c+1] + bta[c+1]);
  o.z = f2bf((v[2]-mean)*rs*g[c+2] + bta[c+2]);
  o.w = f2bf((v[3]-mean)*rs*g[c+3] + bta[c+3]);
  *reinterpret_cast<ushort4*>(xn + (size_t)row*D_DIM + c) = o;
  if (lane == 0) mval[row] = (mask[row] == PAD_TOK) ? 0.0f : 1.0f;
}

// ---------------- Kernel 2a: transpose QKVG weights -> wt[mat][e][d] bf16 ----------------
__global__ __launch_bounds__(256) void k_prep_w(
    const float* __restrict__ Wq, const float* __restrict__ Wk,
    const float* __restrict__ Wv, const float* __restrict__ Wg,
    unsigned short* __restrict__ wt){
  int mat = blockIdx.z; int proj = mat >> 2, h = mat & 3;
  const float* W = (proj==0 ? Wq : (proj==1 ? Wk : (proj==2 ? Wv : Wg))) + (size_t)h * D_DIM * E_DIM;
  __shared__ float tile[64][65];
  int e0 = blockIdx.x*64, d0 = blockIdx.y*64;
  #pragma unroll
  for (int i=0;i<16;i++){
    int idx = threadIdx.x + i*256;
    int dl = idx >> 6, el = idx & 63;
    tile[dl][el] = W[(size_t)(d0+dl)*E_DIM + e0 + el];
  }
  __syncthreads();
  #pragma unroll
  for (int i=0;i<16;i++){
    int idx = threadIdx.x + i*256;
    int el = idx >> 6, dl = idx & 63;
    wt[((size_t)mat*E_DIM + e0+el)*D_DIM + d0+dl] = f2bf(tile[dl][el]);
  }
}

// ------- Kernel 2b: out_w [e*H+h][col] -> owt[col][h*256+e] bf16 (B^T, perm baked) -------
__global__ __launch_bounds__(256) void k_prep_ow(
    const float* __restrict__ out_w, unsigned short* __restrict__ owt){
  int c0 = blockIdx.x*64;            // c' = h*256+e tile base
  int col0 = blockIdx.y*64;
  int hh = c0 >> 8; int e0 = c0 & 255;
  __shared__ float tile[64][65];
  #pragma unroll
  for (int i=0;i<16;i++){
    int idx = threadIdx.x + i*256;
    int el = idx>>6, cl = idx&63;
    tile[el][cl] = out_w[(size_t)((e0+el)*H_HEADS + hh)*E_DIM + col0+cl];
  }
  __syncthreads();
  #pragma unroll
  for (int i=0;i<16;i++){
    int idx = threadIdx.x + i*256;
    int cl = idx>>6, el = idx&63;
    owt[(size_t)(col0+cl)*1024 + c0 + el] = f2bf(tile[el][cl]);
  }
}

// ---------------- Kernel 3: batched projections q,k,gate (+v transposed) ----------------
__global__ __launch_bounds__(256) void k_proj(
    const unsigned short* __restrict__ xn, const unsigned short* __restrict__ wt,
    unsigned short* __restrict__ qb, unsigned short* __restrict__ kb,
    unsigned short* __restrict__ vtb, unsigned short* __restrict__ gpb){
  int mat = blockIdx.y; int proj = mat >> 2, h = mat & 3;
  int wv = threadIdx.x >> 6, lane = threadIdx.x & 63;
  int lr = lane & 15, lg = lane >> 4;
  int r0 = blockIdx.x * 64 + wv * 16;
  const unsigned short* wm = wt + (size_t)mat * D_DIM * E_DIM;
  short8 a[8];
  const unsigned short* arow = xn + (size_t)(r0 + lr) * D_DIM + lg*8;
  #pragma unroll
  for (int kk=0;kk<8;kk++) a[kk] = *reinterpret_cast<const short8*>(arow + kk*32);
  unsigned short* outp = (proj==0 ? qb : (proj==1 ? kb : gpb)) + (size_t)h * ROWS * E_DIM;
  #pragma unroll 4
  for (int nt=0; nt<16; nt++){
    f32x4 acc = f32x4{0.f,0.f,0.f,0.f};
    const unsigned short* brow = wm + (size_t)(nt*16 + lr) * D_DIM + lg*8;
    #pragma unroll
    for (int kk=0;kk<8;kk++){
      short8 bfrag = *reinterpret_cast<const short8*>(brow + kk*32);
      acc = mfma16(a[kk], bfrag, acc);
    }
    int col = nt*16 + lr;
    if (proj == 2){
      #pragma unroll
      for (int r=0;r<4;r++){
        int row = r0 + lg*4 + r;
        int b_ = row >> 11, n_ = row & 2047;
        vtb[(((size_t)(h*B_SZ + b_)*E_DIM + col) << 11) + n_] = f2bf(acc[r]);
      }
    } else {
      #pragma unroll
      for (int r=0;r<4;r++){
        int row = r0 + lg*4 + r;
        outp[(size_t)row*E_DIM + col] = f2bf(acc[r]);
      }
    }
  }
}

// ---------------- Kernel 4: flash attention + gate + residual LN ----------------
__global__ __launch_bounds__(256) void k_attn(
    const unsigned short* __restrict__ qb, const unsigned short* __restrict__ kb,
    const unsigned short* __restrict__ vt, const unsigned short* __restrict__ gp,
    const float* __restrict__ mval, const float* __restrict__ x,
    const float* __restrict__ g_res, const float* __restrict__ b_res,
    unsigned short* __restrict__ attout){
  int hb = blockIdx.y; int h = hb >> 2, bb = hb & 3;
  int wv = threadIdx.x >> 6, lane = threadIdx.x & 63;
  int lr = lane & 15, lg = lane >> 4;
  int n0 = blockIdx.x * 64 + wv * 16;
  const unsigned short* qm = qb + ((size_t)h * ROWS + (size_t)bb * N_SEQ) * E_DIM;
  const unsigned short* km = kb + ((size_t)h * ROWS + (size_t)bb * N_SEQ) * E_DIM;
  const unsigned short* vm = vt + ((size_t)(h * B_SZ + bb)) * E_DIM * N_SEQ;
  const unsigned short* gpm = gp + ((size_t)h * ROWS + (size_t)bb * N_SEQ) * E_DIM;
  const float* mrow = mval + bb * N_SEQ;

  __shared__ alignas(16) unsigned short Klds[32][D_DIM + 8];
  __shared__ alignas(16) unsigned short Vlds[E_DIM][32 + 8];
  __shared__ alignas(16) unsigned short Plds[4][16][32 + 8];

  short8 qf[8];
  {
    const unsigned short* qrow = qm + (size_t)(n0 + lr) * E_DIM + lg * 8;
    #pragma unroll
    for (int kk=0;kk<8;kk++) qf[kk] = *reinterpret_cast<const short8*>(qrow + kk*32);
  }
  f32x4 o[16];
  #pragma unroll
  for (int i=0;i<16;i++) o[i] = f32x4{0.f,0.f,0.f,0.f};
  float mrun[4], lrun[4];
  #pragma unroll
  for (int r=0;r<4;r++){ mrun[r] = -3.0e38f; lrun[r] = 0.f; }

  for (int kt=0; kt<N_SEQ/32; kt++){
    __syncthreads();
    {
      // K tile: 32 rows x 256 cols = 1024 short8 chunks; 256 threads x 4
      #pragma unroll
      for (int i=0;i<4;i++){
        int chunk = threadIdx.x + i*256;
        int rr = chunk >> 5, cc = (chunk & 31) * 8;
        *reinterpret_cast<short8*>(&Klds[rr][cc]) =
            *reinterpret_cast<const short8*>(km + (size_t)(kt*32 + rr)*E_DIM + cc);
      }
      // V^T tile: 256 e-rows x 32 k-cols; thread t stages e-row t
      const unsigned short* vrow = vm + (size_t)threadIdx.x * N_SEQ + kt*32;
      #pragma unroll
      for (int i=0;i<4;i++){
        *reinterpret_cast<short8*>(&Vlds[threadIdx.x][i*8]) =
            *reinterpret_cast<const short8*>(vrow + i*8);
      }
    }
    __syncthreads();
    // S = Q K^T (two 16-col tiles)
    f32x4 s0 = f32x4{0.f,0.f,0.f,0.f}, s1v = f32x4{0.f,0.f,0.f,0.f};
    #pragma unroll
    for (int kk=0;kk<8;kk++){
      short8 b0 = *reinterpret_cast<const short8*>(&Klds[lr][kk*32 + lg*8]);
      short8 b1 = *reinterpret_cast<const short8*>(&Klds[16 + lr][kk*32 + lg*8]);
      s0  = mfma16(qf[kk], b0, s0);
      s1v = mfma16(qf[kk], b1, s1v);
    }
    float mk0 = (mrow[kt*32 + lr] - 1.0f) * 1e9f;
    float mk1 = (mrow[kt*32 + 16 + lr] - 1.0f) * 1e9f;
    float p0[4], p1[4], rmax[4];
    #pragma unroll
    for (int r=0;r<4;r++){
      p0[r] = s0[r]*0.0625f + mk0;
      p1[r] = s1v[r]*0.0625f + mk1;
      rmax[r] = fmaxf(p0[r], p1[r]);
    }
    #pragma unroll
    for (int m=1;m<16;m<<=1){
      #pragma unroll
      for (int r=0;r<4;r++) rmax[r] = fmaxf(rmax[r], __shfl_xor(rmax[r], m, 16));
    }
    float alpha[4], rsum[4];
    #pragma unroll
    for (int r=0;r<4;r++){
      float mnew = fmaxf(mrun[r], rmax[r]);
      alpha[r] = __expf(mrun[r] - mnew);
      mrun[r] = mnew;
      p0[r] = __expf(p0[r] - mnew);
      p1[r] = __expf(p1[r] - mnew);
      rsum[r] = p0[r] + p1[r];
    }
    #pragma unroll
    for (int m=1;m<16;m<<=1){
      #pragma unroll
      for (int r=0;r<4;r++) rsum[r] += __shfl_xor(rsum[r], m, 16);
    }
    #pragma unroll
    for (int r=0;r<4;r++) lrun[r] = lrun[r]*alpha[r] + rsum[r];
    #pragma unroll
    for (int i=0;i<16;i++){
      #pragma unroll
      for (int r=0;r<4;r++) o[i][r] *= alpha[r];
    }
    // P (D-frag layout) -> LDS -> A-frag layout; wave-private buffer
    #pragma unroll
    for (int r=0;r<4;r++){
      Plds[wv][lg*4+r][lr]      = f2bf(p0[r]);
      Plds[wv][lg*4+r][16+lr]   = f2bf(p1[r]);
    }
    short8 pa = *reinterpret_cast<const short8*>(&Plds[wv][lr][lg*8]);
    #pragma unroll
    for (int et=0;et<16;et++){
      short8 bv = *reinterpret_cast<const short8*>(&Vlds[et*16 + lr][lg*8]);
      o[et] = mfma16(pa, bv, o[et]);
    }
  }
  // epilogue: /l, sigmoid gate, +x, LN(g_res,b_res), write head-major bf16
  float inv[4], mm_[4], rs_[4];
  #pragma unroll
  for (int r=0;r<4;r++) inv[r] = (lrun[r] > 0.f) ? (1.0f / lrun[r]) : 0.f;
  float s1_[4] = {0,0,0,0}, s2_[4] = {0,0,0,0};
  #pragma unroll
  for (int et=0;et<16;et++){
    int col = et*16 + lr;
    #pragma unroll
    for (int r=0;r<4;r++){
      int n = n0 + lg*4 + r;
      float ov = o[et][r] * inv[r];
      float gpre = bf2f(gpm[(size_t)n*E_DIM + col]);
      float gate = 1.0f / (1.0f + __expf(-gpre));
      float val = ov * gate + x[((size_t)(bb*N_SEQ + n))*D_DIM + col];
      o[et][r] = val;
      s1_[r] += val; s2_[r] += val*val;
    }
  }
  #pragma unroll
  for (int m=1;m<16;m<<=1){
    #pragma unroll
    for (int r=0;r<4;r++){ s1_[r] += __shfl_xor(s1_[r], m, 16); s2_[r] += __shfl_xor(s2_[r], m, 16); }
  }
  #pragma unroll
  for (int r=0;r<4;r++){
    float mean = s1_[r] * (1.0f/E_DIM);
    float var  = s2_[r] * (1.0f/E_DIM) - mean*mean;
    mm_[r] = mean; rs_[r] = rsqrtf(var + LN_EPS);
  }
  #pragma unroll
  for (int et=0;et<16;et++){
    int col = et*16 + lr;
    float gr = g_res[col], br = b_res[col];
    #pragma unroll
    for (int r=0;r<4;r++){
      int n = n0 + lg*4 + r;
      float y = (o[et][r] - mm_[r]) * rs_[r] * gr + br;
      attout[((size_t)(bb*N_SEQ + n))*1024 + h*256 + col] = f2bf(y);
    }
  }
}

// ---------------- Kernel 5: out proj + bias + residual + LN + mask ----------------
__global__ __launch_bounds__(256) void k_final(
    const unsigned short* __restrict__ attout, const unsigned short* __restrict__ owt,
    const float* __restrict__ out_b, const float* __restrict__ x,
    const float* __restrict__ g_out, const float* __restrict__ b_out,
    const float* __restrict__ mval, float* __restrict__ out){
  int wv = threadIdx.x >> 6, lane = threadIdx.x & 63;
  int lr = lane & 15, lg = lane >> 4;
  int r0 = blockIdx.x * 64 + wv*16;
  int c0 = blockIdx.y * 128;           // two col-halves
  f32x4 acc[8];
  #pragma unroll
  for (int i=0;i<8;i++) acc[i] = f32x4{0.f,0.f,0.f,0.f};
  const unsigned short* arow = attout + (size_t)(r0 + lr)*1024 + lg*8;
  for (int kg=0; kg<4; kg++){
    short8 a[8];
    #pragma unroll
    for (int kk=0;kk<8;kk++) a[kk] = *reinterpret_cast<const short8*>(arow + kg*256 + kk*32);
    #pragma unroll
    for (int nt=0;nt<8;nt++){
      const unsigned short* brow = owt + (size_t)(c0 + nt*16 + lr)*1024 + kg*256 + lg*8;
      #pragma unroll
      for (int kk=0;kk<8;kk++){
        short8 bfrag = *reinterpret_cast<const short8*>(brow + kk*32);
        acc[nt] = mfma16(a[kk], bfrag, acc[nt]);
      }
    }
  }
  // partial LN sums for the 128 cols this block owns; combine via LDS with other col-block?
  // -> block handles its own LN by computing full-row sums: need all 256 cols.
  // Instead: each block computes partial sums and redundant other-half? Simpler: compute
  // full row here anyway (blockIdx.y==0 does cols 0-127, ==1 does 128-255); LN needs the
  // full row, so each block recomputes the row sums from BOTH halves would need the other
  // half's values. To stay simple and correct we let each block compute BOTH halves'
  // values for its rows' LN statistics is wasteful; instead keep grid.y=1 semantics:
  // we restore full 16-tile accumulation when c0==0 and skip when c0==128 is wrong.
  // => Simplest correct: this kernel is launched with grid.y=1 and nt loops 16 tiles.
  // (acc sized 8 kept; second half accumulated in second pass below)
  f32x4 acc2[8];
  #pragma unroll
  for (int i=0;i<8;i++) acc2[i] = f32x4{0.f,0.f,0.f,0.f};
  for (int kg=0; kg<4; kg++){
    short8 a[8];
    #pragma unroll
    for (int kk=0;kk<8;kk++) a[kk] = *reinterpret_cast<const short8*>(arow + kg*256 + kk*32);
    #pragma unroll
    for (int nt=0;nt<8;nt++){
      const unsigned short* brow = owt + (size_t)(128 + nt*16 + lr)*1024 + kg*256 + lg*8;
      #pragma unroll
      for (int kk=0;kk<8;kk++){
        short8 bfrag = *reinterpret_cast<const short8*>(brow + kk*32);
        acc2[nt] = mfma16(a[kk], bfrag, acc2[nt]);
      }
    }
  }
  float s1_[4]={0,0,0,0}, s2_[4]={0,0,0,0};
  #pragma unroll
  for (int nt=0;nt<8;nt++){
    int col = nt*16 + lr;
    float ob = out_b[col], ob2 = out_b[128+col];
    #pragma unroll
    for (int r=0;r<4;r++){
      int row = r0 + lg*4 + r;
      float val = acc[nt][r] + ob + x[(size_t)row*D_DIM + col];
      float val2 = acc2[nt][r] + ob2 + x[(size_t)row*D_DIM + 128 + col];
      acc[nt][r] = val; acc2[nt][r] = val2;
      s1_[r]+=val+val2; s2_[r]+=val*val+val2*val2;
    }
  }
  #pragma unroll
  for (int m=1;m<16;m<<=1){
    #pragma unroll
    for (int r=0;r<4;r++){ s1_[r]+=__shfl_xor(s1_[r],m,16); s2_[r]+=__shfl_xor(s2_[r],m,16); }
  }
  float mm_[4], rs_[4];
  #pragma unroll
  for (int r=0;r<4;r++){
    float mean = s1_[r]*(1.0f/E_DIM);
    float var  = s2_[r]*(1.0f/E_DIM) - mean*mean;
    mm_[r]=mean; rs_[r]=rsqrtf(var + LN_EPS);
  }
  #pragma unroll
  for (int nt=0;nt<8;nt++){
    int col = nt*16 + lr;
    float gg = g_out[col], bb2 = b_out[col];
    float gg2 = g_out[128+col], bb3 = b_out[128+col];
    #pragma unroll
    for (int r=0;r<4;r++){
      int row = r0 + lg*4 + r;
      float mv = mval[row];
      out[(size_t)row*E_DIM + col] = ((acc[nt][r]-mm_[r])*rs_[r]*gg + bb2) * mv;
      out[(size_t)row*E_DIM + 128 + col] = ((acc2[nt][r]-mm_[r])*rs_[r]*gg2 + bb3) * mv;
    }
  }
}

extern "C" void kernel_launch(void* const* d_in, const int* in_sizes, int n_in,
                              void* d_out, int out_size, void* d_ws, size_t ws_size,
                              hipStream_t stream) {
  const float* x     = (const float*)d_in[0];
  const float* mask  = (const float*)d_in[1];
  const float* Wq    = (const float*)d_in[2];
  const float* Wk    = (const float*)d_in[3];
  const float* Wv    = (const float*)d_in[4];
  const float* Wg    = (const float*)d_in[5];
  const float* out_w = (const float*)d_in[6];
  const float* out_b = (const float*)d_in[7];
  const float* g_in  = (const float*)d_in[8];
  const float* b_in  = (const float*)d_in[9];
  const float* g_res = (const float*)d_in[10];
  const float* b_res = (const float*)d_in[11];
  const float* g_out = (const float*)d_in[12];
  const float* b_out = (const float*)d_in[13];

  char* ws = (char*)d_ws;
  size_t off = 0;
  unsigned short* xn   = (unsigned short*)(ws + off); off += (size_t)ROWS * D_DIM * 2;           // 4 MB
  float*          mval = (float*)(ws + off);          off += (size_t)ROWS * 4;                   // 32 KB
  unsigned short* wt   = (unsigned short*)(ws + off); off += (size_t)16 * D_DIM * E_DIM * 2;     // 2 MB
  unsigned short* owt  = (unsigned short*)(ws + off); off += (size_t)E_DIM * 1024 * 2;           // 512 KB
  unsigned short* qb   = (unsigned short*)(ws + off); off += (size_t)H_HEADS * ROWS * E_DIM * 2; // 16 MB
  unsigned short* kb   = (unsigned short*)(ws + off); off += (size_t)H_HEADS * ROWS * E_DIM * 2; // 16 MB
  unsigned short* vtb  = (unsigned short*)(ws + off); off += (size_t)H_HEADS * ROWS * E_DIM * 2; // 16 MB
  unsigned short* gpb  = (unsigned short*)(ws + off); off += (size_t)H_HEADS * ROWS * E_DIM * 2; // 16 MB
  unsigned short* attout = (unsigned short*)(ws + off); off += (size_t)ROWS * 1024 * 2;          // 16 MB

  k_ln_in<<<dim3(ROWS/4), dim3(256), 0, stream>>>(x, mask, g_in, b_in, xn, mval);
  k_prep_w<<<dim3(4,4,16), dim3(256), 0, stream>>>(Wq, Wk, Wv, Wg, wt);
  k_prep_ow<<<dim3(16,4), dim3(256), 0, stream>>>(out_w, owt);
  k_proj<<<dim3(ROWS/64, 16), dim3(256), 0, stream>>>(xn, wt, qb, kb, vtb, gpb);
  k_attn<<<dim3(N_SEQ/64, H_HEADS*B_SZ), dim3(256), 0, stream>>>(qb, kb, vtb, gpb, mval, x, g_res, b_res, attout);
  k_final<<<dim3(ROWS/64), dim3(256), 0, stream>>>(attout, owt, out_b, x, g_out, b_out, mval, (float*)d_out);
}

// Round 3
// 364.454 us; speedup vs baseline: 1.3257x; 1.3257x over previous
//
#include <hip/hip_runtime.h>
#include <math.h>

#define B_SZ 4
#define N_SEQ 2048
#define D_DIM 256
#define H_HEADS 4
#define E_DIM 256
#define ROWS (B_SZ*N_SEQ)
#define PAD_TOK -2.0f
#define LN_EPS 1e-6f

typedef __attribute__((ext_vector_type(8))) short short8;   // 8 x bf16 (4 VGPRs)
typedef __attribute__((ext_vector_type(4))) float f32x4;

static __device__ __forceinline__ unsigned short f2bf(float f){
  union { float f; unsigned u; } v; v.f = f;
  unsigned r = v.u + 0x7fffu + ((v.u >> 16) & 1u);
  return (unsigned short)(r >> 16);
}
static __device__ __forceinline__ float bf2f(unsigned short s){
  union { unsigned u; float f; } v; v.u = ((unsigned)s) << 16; return v.f;
}
static __device__ __forceinline__ f32x4 mfma16(short8 a, short8 b, f32x4 c){
  return __builtin_amdgcn_mfma_f32_16x16x32_bf16(a, b, c, 0, 0, 0);
}

// async global->LDS, 16B per lane; LDS dest must be wave-linear (base + lane*16)
#define GLOAD_LDS16(gsrc, ldst) \
  __builtin_amdgcn_global_load_lds((const __attribute__((address_space(1))) void*)(gsrc), \
                                   (__attribute__((address_space(3))) void*)(ldst), 16, 0, 0)

// ---------------- Kernel 1: input LN -> bf16 x_norm, mask value ----------------
__global__ __launch_bounds__(256) void k_ln_in(
    const float* __restrict__ x, const float* __restrict__ mask,
    const float* __restrict__ g, const float* __restrict__ bta,
    unsigned short* __restrict__ xn, float* __restrict__ mval){
  int row = blockIdx.x * 4 + (threadIdx.x >> 6);
  int lane = threadIdx.x & 63;
  const float* xr = x + (size_t)row * D_DIM + lane * 4;
  f32x4 v = *reinterpret_cast<const f32x4*>(xr);
  float s = v[0]+v[1]+v[2]+v[3];
  float q = v[0]*v[0]+v[1]*v[1]+v[2]*v[2]+v[3]*v[3];
  #pragma unroll
  for (int m=1;m<64;m<<=1){ s += __shfl_xor(s,m,64); q += __shfl_xor(q,m,64); }
  float mean = s * (1.0f/D_DIM);
  float var  = q * (1.0f/D_DIM) - mean*mean;
  float rs = rsqrtf(var + LN_EPS);
  int c = lane*4;
  ushort4 o;
  o.x = f2bf((v[0]-mean)*rs*g[c+0] + bta[c+0]);
  o.y = f2bf((v[1]-mean)*rs*g[c+1] + bta[c+1]);
  o.z = f2bf((v[2]-mean)*rs*g[c+2] + bta[c+2]);
  o.w = f2bf((v[3]-mean)*rs*g[c+3] + bta[c+3]);
  *reinterpret_cast<ushort4*>(xn + (size_t)row*D_DIM + c) = o;
  if (lane == 0) mval[row] = (mask[row] == PAD_TOK) ? 0.0f : 1.0f;
}

// ---------------- Kernel 2a: transpose QKVG weights -> wt[mat][e][d] bf16 ----------------
__global__ __launch_bounds__(256) void k_prep_w(
    const float* __restrict__ Wq, const float* __restrict__ Wk,
    const float* __restrict__ Wv, const float* __restrict__ Wg,
    unsigned short* __restrict__ wt){
  int mat = blockIdx.z; int proj = mat >> 2, h = mat & 3;
  const float* W = (proj==0 ? Wq : (proj==1 ? Wk : (proj==2 ? Wv : Wg))) + (size_t)h * D_DIM * E_DIM;
  __shared__ float tile[64][65];
  int e0 = blockIdx.x*64, d0 = blockIdx.y*64;
  #pragma unroll
  for (int i=0;i<16;i++){
    int idx = threadIdx.x + i*256;
    int dl = idx >> 6, el = idx & 63;
    tile[dl][el] = W[(size_t)(d0+dl)*E_DIM + e0 + el];
  }
  __syncthreads();
  #pragma unroll
  for (int i=0;i<16;i++){
    int idx = threadIdx.x + i*256;
    int el = idx >> 6, dl = idx & 63;
    wt[((size_t)mat*E_DIM + e0+el)*D_DIM + d0+dl] = f2bf(tile[dl][el]);
  }
}

// ------- Kernel 2b: out_w [e*H+h][col] -> owt[col][h*256+e] bf16 (B^T, perm baked) -------
__global__ __launch_bounds__(256) void k_prep_ow(
    const float* __restrict__ out_w, unsigned short* __restrict__ owt){
  int c0 = blockIdx.x*64;            // c' = h*256+e tile base
  int col0 = blockIdx.y*64;
  int hh = c0 >> 8; int e0 = c0 & 255;
  __shared__ float tile[64][65];
  #pragma unroll
  for (int i=0;i<16;i++){
    int idx = threadIdx.x + i*256;
    int el = idx>>6, cl = idx&63;
    tile[el][cl] = out_w[(size_t)((e0+el)*H_HEADS + hh)*E_DIM + col0+cl];
  }
  __syncthreads();
  #pragma unroll
  for (int i=0;i<16;i++){
    int idx = threadIdx.x + i*256;
    int cl = idx>>6, el = idx&63;
    owt[(size_t)(col0+cl)*1024 + c0 + el] = f2bf(tile[el][cl]);
  }
}

// ------- Kernel 3: batched projections q,k,gate (+v transposed); 32 rows/wave -------
__global__ __launch_bounds__(256,2) void k_proj(
    const unsigned short* __restrict__ xn, const unsigned short* __restrict__ wt,
    unsigned short* __restrict__ qb, unsigned short* __restrict__ kb,
    unsigned short* __restrict__ vtb, unsigned short* __restrict__ gpb){
  int mat = blockIdx.y; int proj = mat >> 2, h = mat & 3;
  int wv = threadIdx.x >> 6, lane = threadIdx.x & 63;
  int lr = lane & 15, lg = lane >> 4;
  int r0 = blockIdx.x * 128 + wv * 32;
  const unsigned short* wm = wt + (size_t)mat * D_DIM * E_DIM;
  short8 a[2][8];
  #pragma unroll
  for (int qr=0;qr<2;qr++){
    const unsigned short* arow = xn + (size_t)(r0 + qr*16 + lr) * D_DIM + lg*8;
    #pragma unroll
    for (int kk=0;kk<8;kk++) a[qr][kk] = *reinterpret_cast<const short8*>(arow + kk*32);
  }
  unsigned short* outp = (proj==0 ? qb : (proj==1 ? kb : gpb)) + (size_t)h * ROWS * E_DIM;
  #pragma unroll 2
  for (int nt=0; nt<16; nt++){
    f32x4 acc0 = f32x4{0.f,0.f,0.f,0.f};
    f32x4 acc1 = f32x4{0.f,0.f,0.f,0.f};
    const unsigned short* brow = wm + (size_t)(nt*16 + lr) * D_DIM + lg*8;
    #pragma unroll
    for (int kk=0;kk<8;kk++){
      short8 bfrag = *reinterpret_cast<const short8*>(brow + kk*32);
      acc0 = mfma16(a[0][kk], bfrag, acc0);
      acc1 = mfma16(a[1][kk], bfrag, acc1);
    }
    int col = nt*16 + lr;
    if (proj == 2){
      #pragma unroll
      for (int r=0;r<4;r++){
        int row0 = r0 + lg*4 + r;
        int row1 = row0 + 16;
        vtb[(((size_t)(h*B_SZ + (row0>>11))*E_DIM + col) << 11) + (row0 & 2047)] = f2bf(acc0[r]);
        vtb[(((size_t)(h*B_SZ + (row1>>11))*E_DIM + col) << 11) + (row1 & 2047)] = f2bf(acc1[r]);
      }
    } else {
      #pragma unroll
      for (int r=0;r<4;r++){
        int row0 = r0 + lg*4 + r;
        outp[(size_t)row0*E_DIM + col] = f2bf(acc0[r]);
        outp[(size_t)(row0+16)*E_DIM + col] = f2bf(acc1[r]);
      }
    }
  }
}

// ---------------- Kernel 4: flash attention + gate + residual LN ----------------
// dbuf K (global_load_lds, XOR-swizzled src+read) + dbuf V (reg-staged, padded), 1 barrier/iter
__global__ __launch_bounds__(256,2) void k_attn(
    const unsigned short* __restrict__ qb, const unsigned short* __restrict__ kb,
    const unsigned short* __restrict__ vt, const unsigned short* __restrict__ gp,
    const float* __restrict__ mval, const float* __restrict__ x,
    const float* __restrict__ g_res, const float* __restrict__ b_res,
    unsigned short* __restrict__ attout){
  int hb = blockIdx.y; int h = hb >> 2, bb = hb & 3;
  int tid = threadIdx.x;
  int wv = tid >> 6, lane = tid & 63;
  int lr = lane & 15, lg = lane >> 4;
  int n0 = blockIdx.x * 64 + wv * 16;
  const unsigned short* qm = qb + ((size_t)h * ROWS + (size_t)bb * N_SEQ) * E_DIM;
  const unsigned short* km = kb + ((size_t)h * ROWS + (size_t)bb * N_SEQ) * E_DIM;
  const unsigned short* vm = vt + ((size_t)(h * B_SZ + bb)) * E_DIM * N_SEQ;
  const unsigned short* gpm = gp + ((size_t)h * ROWS + (size_t)bb * N_SEQ) * E_DIM;
  const float* mrow = mval + bb * N_SEQ;

  __shared__ alignas(16) unsigned short Klds[2][32*256];   // linear, XOR-swizzled contents
  __shared__ alignas(16) unsigned short Vlds[2][256][36];  // [e][k] padded
  __shared__ alignas(16) unsigned short Plds[4][16][40];   // per-wave P

  short8 qf[8];
  {
    const unsigned short* qrow = qm + (size_t)(n0 + lr) * E_DIM + lg * 8;
    #pragma unroll
    for (int kk=0;kk<8;kk++) qf[kk] = *reinterpret_cast<const short8*>(qrow + kk*32);
  }
  f32x4 o[16];
  #pragma unroll
  for (int i=0;i<16;i++) o[i] = f32x4{0.f,0.f,0.f,0.f};
  float mrun[4], lrun[4];
  #pragma unroll
  for (int r=0;r<4;r++){ mrun[r] = -1.0e30f; lrun[r] = 0.f; }

  // ---- prologue: stage tile 0 ----
  {
    const char* kg = (const char*)km;   // tile 0, 32x256 bf16 contiguous
    #pragma unroll
    for (int i=0;i<4;i++){
      int c = tid + i*256; int krow = c >> 5;
      unsigned off = ((unsigned)(c*16)) ^ ((unsigned)((krow&7)<<4));
      GLOAD_LDS16(kg + off, (char*)(&Klds[0][0]) + c*16);
    }
    const unsigned short* vr = vm + (size_t)tid * N_SEQ;
    short8 v0[4];
    #pragma unroll
    for (int i=0;i<4;i++) v0[i] = *reinterpret_cast<const short8*>(vr + i*8);
    #pragma unroll
    for (int i=0;i<4;i++) *reinterpret_cast<short8*>(&Vlds[0][tid][i*8]) = v0[i];
  }
  __syncthreads();

  int cur = 0;
  for (int kt=0; kt<N_SEQ/32; kt++){
    int nxt = cur ^ 1;
    short8 vreg[4];
    if (kt < N_SEQ/32 - 1){
      // issue next K tile (async to LDS) and next V tile (to regs)
      const char* kg = (const char*)(km + (size_t)(kt+1)*32*E_DIM);
      #pragma unroll
      for (int i=0;i<4;i++){
        int c = tid + i*256; int krow = c >> 5;
        unsigned off = ((unsigned)(c*16)) ^ ((unsigned)((krow&7)<<4));
        GLOAD_LDS16(kg + off, (char*)(&Klds[nxt][0]) + c*16);
      }
      const unsigned short* vr = vm + (size_t)tid * N_SEQ + (kt+1)*32;
      #pragma unroll
      for (int i=0;i<4;i++) vreg[i] = *reinterpret_cast<const short8*>(vr + i*8);
    }
    // ---- QK^T on current tile ----
    const char* kbase = (const char*)(&Klds[cur][0]);
    f32x4 s0 = f32x4{0.f,0.f,0.f,0.f}, s1v = f32x4{0.f,0.f,0.f,0.f};
    unsigned swz = (unsigned)((lr&7)<<4);
    #pragma unroll
    for (int kk=0;kk<8;kk++){
      short8 b0 = *reinterpret_cast<const short8*>(kbase + ((unsigned)(lr*512 + kk*64 + lg*16) ^ swz));
      short8 b1 = *reinterpret_cast<const short8*>(kbase + ((unsigned)((16+lr)*512 + kk*64 + lg*16) ^ swz));
      s0  = mfma16(qf[kk], b0, s0);
      s1v = mfma16(qf[kk], b1, s1v);
    }
    float mk0 = (mrow[kt*32 + lr] - 1.0f) * 1e9f;
    float mk1 = (mrow[kt*32 + 16 + lr] - 1.0f) * 1e9f;
    float p0[4], p1[4], tmax[4];
    #pragma unroll
    for (int r=0;r<4;r++){
      p0[r] = s0[r]*0.0625f + mk0;
      p1[r] = s1v[r]*0.0625f + mk1;
      tmax[r] = fmaxf(p0[r], p1[r]);
    }
    #pragma unroll
    for (int m=1;m<16;m<<=1){
      #pragma unroll
      for (int r=0;r<4;r++) tmax[r] = fmaxf(tmax[r], __shfl_xor(tmax[r], m, 16));
    }
    // defer-max: only rescale when tile max grows past mrun + 8
    bool need = false;
    #pragma unroll
    for (int r=0;r<4;r++) need = need || (tmax[r] > mrun[r] + 8.0f);
    if (__any((int)need)){
      #pragma unroll
      for (int r=0;r<4;r++){
        float mnew = fmaxf(mrun[r], tmax[r]);
        float alpha = __expf(mrun[r] - mnew);
        mrun[r] = mnew;
        lrun[r] *= alpha;
        #pragma unroll
        for (int i=0;i<16;i++) o[i][r] *= alpha;
      }
    }
    float rsum[4];
    #pragma unroll
    for (int r=0;r<4;r++){
      p0[r] = __expf(p0[r] - mrun[r]);
      p1[r] = __expf(p1[r] - mrun[r]);
      rsum[r] = p0[r] + p1[r];
    }
    #pragma unroll
    for (int m=1;m<16;m<<=1){
      #pragma unroll
      for (int r=0;r<4;r++) rsum[r] += __shfl_xor(rsum[r], m, 16);
    }
    #pragma unroll
    for (int r=0;r<4;r++) lrun[r] += rsum[r];
    // P -> LDS (wave-private) -> A-frag
    #pragma unroll
    for (int r=0;r<4;r++){
      Plds[wv][lg*4+r][lr]      = f2bf(p0[r]);
      Plds[wv][lg*4+r][16+lr]   = f2bf(p1[r]);
    }
    short8 pa = *reinterpret_cast<const short8*>(&Plds[wv][lr][lg*8]);
    // ---- PV ----
    #pragma unroll
    for (int et=0;et<16;et++){
      short8 bv = *reinterpret_cast<const short8*>(&Vlds[cur][et*16 + lr][lg*8]);
      o[et] = mfma16(pa, bv, o[et]);
    }
    // write next V tile (regs landed during compute)
    if (kt < N_SEQ/32 - 1){
      #pragma unroll
      for (int i=0;i<4;i++) *reinterpret_cast<short8*>(&Vlds[nxt][tid][i*8]) = vreg[i];
    }
    __syncthreads();
    cur = nxt;
  }
  // epilogue: /l, sigmoid gate, +x, LN(g_res,b_res), write head-major bf16
  float inv[4], mm_[4], rs_[4];
  #pragma unroll
  for (int r=0;r<4;r++) inv[r] = (lrun[r] > 0.f) ? (1.0f / lrun[r]) : 0.f;
  float s1_[4] = {0,0,0,0}, s2_[4] = {0,0,0,0};
  #pragma unroll
  for (int et=0;et<16;et++){
    int col = et*16 + lr;
    #pragma unroll
    for (int r=0;r<4;r++){
      int n = n0 + lg*4 + r;
      float ov = o[et][r] * inv[r];
      float gpre = bf2f(gpm[(size_t)n*E_DIM + col]);
      float gate = 1.0f / (1.0f + __expf(-gpre));
      float val = ov * gate + x[((size_t)(bb*N_SEQ + n))*D_DIM + col];
      o[et][r] = val;
      s1_[r] += val; s2_[r] += val*val;
    }
  }
  #pragma unroll
  for (int m=1;m<16;m<<=1){
    #pragma unroll
    for (int r=0;r<4;r++){ s1_[r] += __shfl_xor(s1_[r], m, 16); s2_[r] += __shfl_xor(s2_[r], m, 16); }
  }
  #pragma unroll
  for (int r=0;r<4;r++){
    float mean = s1_[r] * (1.0f/E_DIM);
    float var  = s2_[r] * (1.0f/E_DIM) - mean*mean;
    mm_[r] = mean; rs_[r] = rsqrtf(var + LN_EPS);
  }
  #pragma unroll
  for (int et=0;et<16;et++){
    int col = et*16 + lr;
    float gr = g_res[col], br = b_res[col];
    #pragma unroll
    for (int r=0;r<4;r++){
      int n = n0 + lg*4 + r;
      float y = (o[et][r] - mm_[r]) * rs_[r] * gr + br;
      attout[((size_t)(bb*N_SEQ + n))*1024 + h*256 + col] = f2bf(y);
    }
  }
}

// ---------------- Kernel 5: out proj + bias + residual + LN + mask ----------------
__global__ __launch_bounds__(128) void k_final(
    const unsigned short* __restrict__ attout, const unsigned short* __restrict__ owt,
    const float* __restrict__ out_b, const float* __restrict__ x,
    const float* __restrict__ g_out, const float* __restrict__ b_out,
    const float* __restrict__ mval, float* __restrict__ out){
  int wv = threadIdx.x >> 6, lane = threadIdx.x & 63;
  int lr = lane & 15, lg = lane >> 4;
  int r0 = blockIdx.x * 32 + wv*16;
  f32x4 acc[16];
  #pragma unroll
  for (int i=0;i<16;i++) acc[i] = f32x4{0.f,0.f,0.f,0.f};
  const unsigned short* arow = attout + (size_t)(r0 + lr)*1024 + lg*8;
  for (int kg=0; kg<4; kg++){
    short8 a[8];
    #pragma unroll
    for (int kk=0;kk<8;kk++) a[kk] = *reinterpret_cast<const short8*>(arow + kg*256 + kk*32);
    #pragma unroll
    for (int nt=0;nt<16;nt++){
      const unsigned short* brow = owt + (size_t)(nt*16 + lr)*1024 + kg*256 + lg*8;
      #pragma unroll
      for (int kk=0;kk<8;kk++){
        short8 bfrag = *reinterpret_cast<const short8*>(brow + kk*32);
        acc[nt] = mfma16(a[kk], bfrag, acc[nt]);
      }
    }
  }
  float s1_[4]={0,0,0,0}, s2_[4]={0,0,0,0};
  #pragma unroll
  for (int nt=0;nt<16;nt++){
    int col = nt*16 + lr;
    float ob = out_b[col];
    #pragma unroll
    for (int r=0;r<4;r++){
      int row = r0 + lg*4 + r;
      float val = acc[nt][r] + ob + x[(size_t)row*D_DIM + col];
      acc[nt][r] = val;
      s1_[r]+=val; s2_[r]+=val*val;
    }
  }
  #pragma unroll
  for (int m=1;m<16;m<<=1){
    #pragma unroll
    for (int r=0;r<4;r++){ s1_[r]+=__shfl_xor(s1_[r],m,16); s2_[r]+=__shfl_xor(s2_[r],m,16); }
  }
  float mm_[4], rs_[4];
  #pragma unroll
  for (int r=0;r<4;r++){
    float mean = s1_[r]*(1.0f/E_DIM);
    float var  = s2_[r]*(1.0f/E_DIM) - mean*mean;
    mm_[r]=mean; rs_[r]=rsqrtf(var + LN_EPS);
  }
  #pragma unroll
  for (int nt=0;nt<16;nt++){
    int col = nt*16 + lr;
    float gg = g_out[col], bb2 = b_out[col];
    #pragma unroll
    for (int r=0;r<4;r++){
      int row = r0 + lg*4 + r;
      float y = ((acc[nt][r]-mm_[r])*rs_[r]*gg + bb2) * mval[row];
      out[(size_t)row*E_DIM + col] = y;
    }
  }
}

extern "C" void kernel_launch(void* const* d_in, const int* in_sizes, int n_in,
                              void* d_out, int out_size, void* d_ws, size_t ws_size,
                              hipStream_t stream) {
  const float* x     = (const float*)d_in[0];
  const float* mask  = (const float*)d_in[1];
  const float* Wq    = (const float*)d_in[2];
  const float* Wk    = (const float*)d_in[3];
  const float* Wv    = (const float*)d_in[4];
  const float* Wg    = (const float*)d_in[5];
  const float* out_w = (const float*)d_in[6];
  const float* out_b = (const float*)d_in[7];
  const float* g_in  = (const float*)d_in[8];
  const float* b_in  = (const float*)d_in[9];
  const float* g_res = (const float*)d_in[10];
  const float* b_res = (const float*)d_in[11];
  const float* g_out = (const float*)d_in[12];
  const float* b_out = (const float*)d_in[13];

  char* ws = (char*)d_ws;
  size_t off = 0;
  unsigned short* xn   = (unsigned short*)(ws + off); off += (size_t)ROWS * D_DIM * 2;           // 4 MB
  float*          mval = (float*)(ws + off);          off += (size_t)ROWS * 4;                   // 32 KB
  unsigned short* wt   = (unsigned short*)(ws + off); off += (size_t)16 * D_DIM * E_DIM * 2;     // 2 MB
  unsigned short* owt  = (unsigned short*)(ws + off); off += (size_t)E_DIM * 1024 * 2;           // 512 KB
  unsigned short* qb   = (unsigned short*)(ws + off); off += (size_t)H_HEADS * ROWS * E_DIM * 2; // 16 MB
  unsigned short* kb   = (unsigned short*)(ws + off); off += (size_t)H_HEADS * ROWS * E_DIM * 2; // 16 MB
  unsigned short* vtb  = (unsigned short*)(ws + off); off += (size_t)H_HEADS * ROWS * E_DIM * 2; // 16 MB
  unsigned short* gpb  = (unsigned short*)(ws + off); off += (size_t)H_HEADS * ROWS * E_DIM * 2; // 16 MB
  unsigned short* attout = (unsigned short*)(ws + off); off += (size_t)ROWS * 1024 * 2;          // 16 MB

  k_ln_in<<<dim3(ROWS/4), dim3(256), 0, stream>>>(x, mask, g_in, b_in, xn, mval);
  k_prep_w<<<dim3(4,4,16), dim3(256), 0, stream>>>(Wq, Wk, Wv, Wg, wt);
  k_prep_ow<<<dim3(16,4), dim3(256), 0, stream>>>(out_w, owt);
  k_proj<<<dim3(ROWS/128, 16), dim3(256), 0, stream>>>(xn, wt, qb, kb, vtb, gpb);
  k_attn<<<dim3(N_SEQ/64, H_HEADS*B_SZ), dim3(256), 0, stream>>>(qb, kb, vtb, gpb, mval, x, g_res, b_res, attout);
  k_final<<<dim3(ROWS/32), dim3(128), 0, stream>>>(attout, owt, out_b, x, g_out, b_out, mval, (float*)d_out);
}